// Round 1
// baseline (159.321 us; speedup 1.0000x reference)
//
#include <hip/hip_runtime.h>

#define R_    512
#define K_    17
#define HIN   56
#define WIN   56
#define OUTS  96
#define NMAP  (R_ * K_)
#define NT    384     // 6 waves/block; LDS still caps at 3 blocks/CU -> 18 waves/CU (was 9)
#define RST   98      // tmp row stride in v2f units (784 B: 16B-aligned, banks stagger by 4)
#define TROWS 60      // phys rows: 0,1 = pad(row0); 2..57 = rows 0..55; 58,59 = pad(row55)

typedef float v2f __attribute__((ext_vector_type(2)));

constexpr float cubic_c(float xin) {
    float x = xin < 0.0f ? -xin : xin;
    const float A = -0.75f;
    if (x <= 1.0f) return ((A + 2.0f) * x - (A + 3.0f)) * x * x + 1.0f;
    if (x < 2.0f)  return A * (((x - 5.0f) * x + 8.0f) * x - 4.0f);
    return 0.0f;
}

// X-pass: folded effective weights on contiguous window [s, s+3] (border clamp folded).
struct XTabT {
    float w[OUTS][4];
    int   s[OUTS];
    constexpr XTabT() : w{}, s{} {
        for (int o = 0; o < OUTS; ++o) {
            float src = ((float)o + 0.5f) * (56.0f / 96.0f) - 0.5f;
            int base = (int)src;
            if ((float)base > src) --base;
            int st = base - 1;
            if (st < 0) st = 0;
            if (st > HIN - 4) st = HIN - 4;
            s[o] = st;
            for (int q = 0; q < 4; ++q) {
                int tap = base - 1 + q;
                float wt = cubic_c(src - (float)tap);
                int p = tap < 0 ? 0 : (tap > HIN - 1 ? HIN - 1 : tap);
                w[o][p - st] += wt;
            }
        }
    }
};
constexpr XTabT XT;

// Y-pass: period-12 raw weights + relative tap start d (logical tap0 row = 7*(h/12)+d[h%12]).
// Border handled by replicated pad rows in tmp (validated: prior session absmax 0.0).
struct YTabT {
    float w[12][4];
    int   d[12];
    constexpr YTabT() : w{}, d{} {
        for (int ph = 0; ph < 12; ++ph) {
            float src = ((float)ph + 0.5f) * (56.0f / 96.0f) - 0.5f;
            int base = (int)src;
            if ((float)base > src) --base;
            d[ph] = base - 1;
            for (int q = 0; q < 4; ++q)
                w[ph][q] = cubic_c(src - (float)(base - 1 + q));
        }
    }
};
constexpr YTabT YT;

// ---- phase 1: x-resize one row of BOTH maps, 16-col group G (6 groups), all pk ops ----
// Window containment (verified against XT.s ranges):
//   G0: s in [0,7]   -> floats  0..11 (FS=0,  NF=3)
//   G1: s in [8,16]  -> floats  8..19 (FS=2,  NF=3)
//   G2: s in [17,26] -> floats 16..31 (FS=4,  NF=4)
//   G3: s in [26,35] -> floats 24..39 (FS=6,  NF=4)
//   G4: s in [36,44] -> floats 36..47 (FS=9,  NF=3)
//   G5: s in [45,52] -> floats 44..55 (FS=11, NF=3)
template<int G>
__device__ __forceinline__ void p1_cols(const float* __restrict__ r0,
                                        const float* __restrict__ r1,
                                        v2f* __restrict__ dst) {
    constexpr int FS = (G == 0) ? 0 : (G == 1) ? 2 : (G == 2) ? 4
                     : (G == 3) ? 6 : (G == 4) ? 9 : 11;
    constexpr int NF = (G == 2 || G == 3) ? 4 : 3;
    v2f rr[NF * 4];
    const float4* A = (const float4*)r0 + FS;
    const float4* B = (const float4*)r1 + FS;
#pragma unroll
    for (int i = 0; i < NF; ++i) {
        float4 a = A[i], b = B[i];
        rr[4 * i + 0] = (v2f){a.x, b.x};
        rr[4 * i + 1] = (v2f){a.y, b.y};
        rr[4 * i + 2] = (v2f){a.z, b.z};
        rr[4 * i + 3] = (v2f){a.w, b.w};
    }
#pragma unroll
    for (int i = 0; i < 8; ++i) {
        const int o0 = 16 * G + 2 * i, o1 = o0 + 1;
        const int s0 = XT.s[o0] - 4 * FS, s1 = XT.s[o1] - 4 * FS;
        v2f a0 = rr[s0] * (v2f){XT.w[o0][0], XT.w[o0][0]};
        a0 = __builtin_elementwise_fma((v2f){XT.w[o0][1], XT.w[o0][1]}, rr[s0 + 1], a0);
        a0 = __builtin_elementwise_fma((v2f){XT.w[o0][2], XT.w[o0][2]}, rr[s0 + 2], a0);
        a0 = __builtin_elementwise_fma((v2f){XT.w[o0][3], XT.w[o0][3]}, rr[s0 + 3], a0);
        v2f a1 = rr[s1] * (v2f){XT.w[o1][0], XT.w[o1][0]};
        a1 = __builtin_elementwise_fma((v2f){XT.w[o1][1], XT.w[o1][1]}, rr[s1 + 1], a1);
        a1 = __builtin_elementwise_fma((v2f){XT.w[o1][2], XT.w[o1][2]}, rr[s1 + 2], a1);
        a1 = __builtin_elementwise_fma((v2f){XT.w[o1][3], XT.w[o1][3]}, rr[s1 + 3], a1);
        float4 st = {a0.x, a0.y, a1.x, a1.y};
        *(float4*)(dst + 2 * i) = st;               // ds_write_b128, 16B-aligned
    }
}

// ---- y-value for (col pair, hh within quarter): quarter q covers out rows 24q..24q+23;
// c[] base = phys row 14q, so relative tap0 = 7*(hh/12) + d[hh%12] + 2 in [0,14]; +3 -> c[18].
// Bit-identical chain used by scan and rescan.
__device__ __forceinline__ v2f yv(const v2f* __restrict__ c, int hh) {
    const int ph = hh % 12, bb = hh / 12;
    const int i0 = 7 * bb + YT.d[ph] + 2;           // const after unroll
    v2f acc = c[i0] * (v2f){YT.w[ph][0], YT.w[ph][0]};
    acc = __builtin_elementwise_fma((v2f){YT.w[ph][1], YT.w[ph][1]}, c[i0 + 1], acc);
    acc = __builtin_elementwise_fma((v2f){YT.w[ph][2], YT.w[ph][2]}, c[i0 + 2], acc);
    acc = __builtin_elementwise_fma((v2f){YT.w[ph][3], YT.w[ph][3]}, c[i0 + 3], acc);
    return acc;
}

__global__ __launch_bounds__(NT)
void _Keypointer_kernel(const float* __restrict__ masks,
                        const float* __restrict__ boxes,
                        float* __restrict__ out) {
    __shared__ __align__(16) v2f tmp[TROWS * RST];  // 47,040 B -> still 3 blocks/CU
    __shared__ v2f wmax[6];
    __shared__ int candp[2];

    const int t   = threadIdx.x;
    const int bm0 = 2 * blockIdx.x;
    const int g   = t >> 6;                         // col group (wave-uniform, 0..5)
    const int w   = t & 63;

    // ---- phase 1: row per lane, 16-col group per wave; pads produced by edge/extra lanes ----
    const int srcrow = min(max(w - 2, 0), HIN - 1);
    const int phys   = min(w, TROWS - 1);           // lanes 60..63 dup lane 59 (same data)
    const float* r0 = masks + (size_t)bm0 * (HIN * WIN) + srcrow * WIN;
    const float* r1 = r0 + HIN * WIN;
    v2f* dst = tmp + phys * RST + 16 * g;
    if      (g == 0) p1_cols<0>(r0, r1, dst);
    else if (g == 1) p1_cols<1>(r0, r1, dst);
    else if (g == 2) p1_cols<2>(r0, r1, dst);
    else if (g == 3) p1_cols<3>(r0, r1, dst);
    else if (g == 4) p1_cols<4>(r0, r1, dst);
    else             p1_cols<5>(r0, r1, dst);

    if (t == 0) { candp[0] = 0x7fffffff; candp[1] = 0x7fffffff; }
    __syncthreads();

    // ---- phase 2: thread = (col, row-quarter), both maps packed in v2f ----
    const int q    = t / 96;                        // 0..3
    const int col  = t - 96 * q;
    const int h0   = 24 * q;
    const v2f* cb  = tmp + (14 * q) * RST + col;
    v2f c[18];
#pragma unroll
    for (int i = 0; i < 18; ++i) c[i] = cb[i * RST];   // ds_read_b64, imm offsets

    v2f vmax = {-INFINITY, -INFINITY};
#pragma unroll
    for (int hh = 0; hh < 24; ++hh)
        vmax = __builtin_elementwise_max(vmax, yv(c, hh));

    // block max per map (per-wave shuffle tree, then 6-entry LDS combine)
    float m0 = vmax.x, m1 = vmax.y;
#pragma unroll
    for (int off = 32; off > 0; off >>= 1) {
        m0 = fmaxf(m0, __shfl_down(m0, off, 64));
        m1 = fmaxf(m1, __shfl_down(m1, off, 64));
    }
    if (w == 0) wmax[g] = (v2f){m0, m1};
    __syncthreads();

    const float M0 = fmaxf(fmaxf(fmaxf(wmax[0].x, wmax[1].x), fmaxf(wmax[2].x, wmax[3].x)),
                           fmaxf(wmax[4].x, wmax[5].x));
    const float M1 = fmaxf(fmaxf(fmaxf(wmax[0].y, wmax[1].y), fmaxf(wmax[2].y, wmax[3].y)),
                           fmaxf(wmax[4].y, wmax[5].y));

    // sparse rescan: only threads whose (col, quarter) contained the max participate
    if (vmax.x == M0 || vmax.y == M1) {
        int c0 = 0x7fffffff, c1 = 0x7fffffff;
#pragma unroll
        for (int hh = 0; hh < 24; ++hh) {
            v2f a = yv(c, hh);                      // bit-identical recompute
            int fp = (h0 + hh) * OUTS + col;
            if (a.x == M0) c0 = min(c0, fp);
            if (a.y == M1) c1 = min(c1, fp);
        }
        if (c0 != 0x7fffffff) atomicMin(&candp[0], c0);
        if (c1 != 0x7fffffff) atomicMin(&candp[1], c1);
    }
    __syncthreads();

    if (t < 2) {
        const int map = bm0 + t;
        const float M = t ? M1 : M0;
        const int bp  = candp[t];
        const int r = map / K_, k = map - r * K_;
        const int y = bp / OUTS, x = bp - y * OUTS;
        const float b0f = boxes[r * 4 + 0], b1f = boxes[r * 4 + 1];
        const float b2f = boxes[r * 4 + 2], b3f = boxes[r * 4 + 3];
        const float corr0 = fmaxf(b2f - b0f, 1.0f) / (float)OUTS;
        const float corr1 = fmaxf(b3f - b1f, 1.0f) / (float)OUTS;
        const float p0 = ((float)y + 0.5f) * corr0 + b0f;
        const float p1 = ((float)x + 0.5f) * corr1 + b1f;
        out[(r * 3 + 0) * K_ + k] = p0;
        out[(r * 3 + 1) * K_ + k] = p1;
        out[(r * 3 + 2) * K_ + k] = 1.0f;
        out[R_ * 3 * K_ + r * K_ + k] = M;
    }
}

extern "C" void kernel_launch(void* const* d_in, const int* in_sizes, int n_in,
                              void* d_out, int out_size, void* d_ws, size_t ws_size,
                              hipStream_t stream) {
    const float* masks = (const float*)d_in[0];
    const float* boxes = (const float*)d_in[1];
    float* out = (float*)d_out;
    _Keypointer_kernel<<<NMAP / 2, NT, 0, stream>>>(masks, boxes, out);
}